// Round 9
// baseline (675.761 us; speedup 1.0000x reference)
//
#include <hip/hip_runtime.h>

// QKVAttentionLegacy on MI355X. qkv f32 (8,1536,2048) = 64 heads x [192][2048]:
// q rows 0:64, k 64:128, v 128:192, channel-major [c][pos].
// out[head][c][t] = sum_s softmax_s(qk/8)[t][s] v[c][s].
// R9: occupancy fix at constant L1 traffic. WG = 4 waves (256 thr); wave-pair 0
// handles s-tiles 0..15, pair 1 handles 16..31, SAME (head, 128-t block).
// Grid 1024 -> 16 waves/CU = 4 waves/SIMD (2x R8) with the barrier-free loop.
// Legal: fixed-shift softmax => partial (O, l) combine by summation; O merged
// via LDS RMW, l via LDS buffer, normalization at the final store.
// Kept: prep -> bf16 frag-major K/V + pre-swizzled Q (exp scale folded),
// direct-from-global MFMA operands, 32x32x16 MFMA, 64 t-rows/wave, in-register
// P via cvt_pk+permlane32_swap, native v_exp, no setprio.

typedef __bf16 bf16;
typedef __bf16 bf16x4 __attribute__((ext_vector_type(4)));
typedef __bf16 bf16x8 __attribute__((ext_vector_type(8)));
typedef float  f32x4  __attribute__((ext_vector_type(4)));
typedef float  f32x16 __attribute__((ext_vector_type(16)));
typedef unsigned int u32;

#define NLEN 2048
#define DCH  64
#define HSTR (NLEN * DCH * 2)          // 256 KB per head per array (bytes)
#define WS_K (16u * 1024u * 1024u)
#define WS_V (32u * 1024u * 1024u)
#define WS_NEED (48u * 1024u * 1024u)
// sqrt(0.125 * log2(e)) -- q,k each scaled by this in prep, so S = (qk/8)*log2e
#define PSCALE 0.42466119f

// 128-byte rows, 16B-granule XOR swizzle (involution): G' = G ^ (row&7)  [Q only]
__device__ __forceinline__ int swzK(int row, int cb) {
    return row * 128 + ((((cb >> 4) ^ row) & 7) << 4) + (cb & 15);
}
// 512-byte f32 rows for the output transpose buffer
__device__ __forceinline__ int swzO(int row, int cb) {
    int g = cb >> 4;
    g = (g & ~7) | ((g ^ row) & 7);
    return row * 512 + (g << 4) + (cb & 15);
}

__device__ __forceinline__ void gload16(const char* g, char* l) {
    __builtin_amdgcn_global_load_lds((const __attribute__((address_space(1))) void*)g,
                                     (__attribute__((address_space(3))) void*)l, 16, 0, 0);
}

// ---------------- prep ----------------
// Q: bf16 scaled, transposed [t][c], XOR-pre-swizzled (consumed via LDS once).
// K: bf16 scaled, frag-major per 64-s tile: [kc:4][rh:2][hi:2][ll5:32][8 bf16]
//    holding K[s = rh*32+ll5][c = kc*16+hi*8+b]  (A-operand of QK, coalesced).
// V: bf16 unscaled, frag-major per 64-s tile: [ks:4][rh:2][hi:2][ll5:32][8 bf16]
//    holding V[c = rh*32+ll5][s = ks*16+hi*8+b]  (B-operand of PV, coalesced).
__global__ __launch_bounds__(256)
void prep(const float* __restrict__ qkv, char* __restrict__ ws)
{
    const int tid  = threadIdx.x;
    const int pb   = blockIdx.x;    // 64-pos block (0..31)
    const int head = blockIdx.y;    // 0..63
    const int type = blockIdx.z;    // 0=q 1=k 2=v

    const float* src = qkv + (size_t)head * (3 * DCH) * NLEN + (size_t)type * DCH * NLEN;
    char* dst = ws + (type == 0 ? 0u : (type == 1 ? WS_K : WS_V))
                   + (size_t)head * HSTR + (size_t)pb * 8192;

    if (type < 2) {
        __shared__ float T[64][65];   // [pos][c], +1 pad
        #pragma unroll
        for (int p = 0; p < 4; ++p) {
            int idx = tid + p * 256;
            int c = idx >> 4, q4 = idx & 15;
            float4 f = *(const float4*)(src + (size_t)c * NLEN + pb * 64 + q4 * 4);
            T[q4 * 4 + 0][c] = f.x * PSCALE;
            T[q4 * 4 + 1][c] = f.y * PSCALE;
            T[q4 * 4 + 2][c] = f.z * PSCALE;
            T[q4 * 4 + 3][c] = f.w * PSCALE;
        }
        __syncthreads();
        #pragma unroll
        for (int p = 0; p < 2; ++p) {
            int gidx = tid + p * 256;
            int s = gidx >> 3, G = gidx & 7;
            if (type == 0) {
                int c0 = (G ^ (s & 7)) * 8;          // pre-swizzled [t][c]
                bf16 tmp[8];
                #pragma unroll
                for (int j = 0; j < 8; ++j) tmp[j] = (bf16)T[s][c0 + j];
                *(bf16x8*)(dst + s * 128 + G * 16) = *(bf16x8*)tmp;
            } else {
                // frag-major K: c-elems G*8..G*8+7 of row s
                const int kc = G >> 1, hi = G & 1;
                bf16 tmp[8];
                #pragma unroll
                for (int j = 0; j < 8; ++j) tmp[j] = (bf16)T[s][G * 8 + j];
                *(bf16x8*)(dst + kc * 2048 + ((s >> 5) & 1) * 1024 + hi * 512
                               + (s & 31) * 16) = *(bf16x8*)tmp;
            }
        }
    } else {
        const int c = tid >> 2, m = tid & 3;      // m = ks
        const float* sp = src + (size_t)c * NLEN + pb * 64 + m * 16;
        float f[16];
        #pragma unroll
        for (int j = 0; j < 4; ++j) *(f32x4*)(f + 4 * j) = *(const f32x4*)(sp + 4 * j);
        #pragma unroll
        for (int gl = 0; gl < 2; ++gl) {          // gl = hi
            bf16 tmp[8];
            #pragma unroll
            for (int j = 0; j < 8; ++j) tmp[j] = (bf16)f[gl * 8 + j];
            *(bf16x8*)(dst + m * 2048 + ((c >> 5) & 1) * 1024 + gl * 512
                           + (c & 31) * 16) = *(bf16x8*)tmp;
        }
    }
}

// exp2 + l-sum + cvt_pk/permlane32_swap: S-half (rows 0-31 = slo, 32-63 = shi,
// one t-half) -> A-operand fragments pa[0..3]
__device__ __forceinline__ void expcvt(f32x16& slo, f32x16& shi, float& l, bf16x8 pa[4])
{
    float a = 0.f, b = 0.f, c = 0.f, d = 0.f;
    #pragma unroll
    for (int r = 0; r < 16; r += 4) {
        slo[r+0] = __builtin_amdgcn_exp2f(slo[r+0]); a += slo[r+0];
        slo[r+1] = __builtin_amdgcn_exp2f(slo[r+1]); b += slo[r+1];
        slo[r+2] = __builtin_amdgcn_exp2f(slo[r+2]); c += slo[r+2];
        slo[r+3] = __builtin_amdgcn_exp2f(slo[r+3]); d += slo[r+3];
    }
    #pragma unroll
    for (int r = 0; r < 16; r += 4) {
        shi[r+0] = __builtin_amdgcn_exp2f(shi[r+0]); a += shi[r+0];
        shi[r+1] = __builtin_amdgcn_exp2f(shi[r+1]); b += shi[r+1];
        shi[r+2] = __builtin_amdgcn_exp2f(shi[r+2]); c += shi[r+2];
        shi[r+3] = __builtin_amdgcn_exp2f(shi[r+3]); d += shi[r+3];
    }
    l += (a + b) + (c + d);
    #pragma unroll
    for (int ks = 0; ks < 4; ++ks) {
        const f32x16& pp = (ks < 2) ? slo : shi;
        const int rb = (ks & 1) * 8;
        u32 X, X2, Y, Y2;
        asm("v_cvt_pk_bf16_f32 %0, %1, %2" : "=v"(X)  : "v"(pp[rb + 0]), "v"(pp[rb + 1]));
        asm("v_cvt_pk_bf16_f32 %0, %1, %2" : "=v"(X2) : "v"(pp[rb + 2]), "v"(pp[rb + 3]));
        asm("v_cvt_pk_bf16_f32 %0, %1, %2" : "=v"(Y)  : "v"(pp[rb + 4]), "v"(pp[rb + 5]));
        asm("v_cvt_pk_bf16_f32 %0, %1, %2" : "=v"(Y2) : "v"(pp[rb + 6]), "v"(pp[rb + 7]));
        asm("v_permlane32_swap_b32 %0, %1" : "+v"(X),  "+v"(Y));
        asm("v_permlane32_swap_b32 %0, %1" : "+v"(X2), "+v"(Y2));
        u32 wds[4] = {X, X2, Y, Y2};
        pa[ks] = *(bf16x8*)wds;
    }
}

// ---------------- main: 128 t/WG, 4 waves (2 t-halves x 2 s-halves) ----------------
__global__ __launch_bounds__(256, 4)
void attn_main(const char* __restrict__ ws, float* __restrict__ out)
{
    const int tid  = threadIdx.x;
    const int lane = tid & 63;
    const int w    = tid >> 6;     // wave 0..3
    const int wt   = w & 1;        // t-half: rows [wt*64, wt*64+64)
    const int wp   = w >> 1;       // s-half: tiles [wp*16, wp*16+16)
    const int hi   = lane >> 5;
    const int ll5  = lane & 31;

    // bid&7 = XCD (round-robin dispatch). Per XCD: j in 0..127; co-resident WGs
    // (j, j+32, j+64, j+96) share a head -> K/V tiles are L1/L2 temporal hits.
    const int bid  = blockIdx.x;
    const int j    = bid >> 3;
    const int head = (bid & 7) * 8 + (j & 7);
    const int tblk = j >> 3;       // 0..15
    const int t0   = tblk * 128;

    const char* Qb = ws + (size_t)head * HSTR + (size_t)t0 * 128;
    const char* Kb = ws + WS_K + (size_t)head * HSTR;
    const char* Vb = ws + WS_V + (size_t)head * HSTR;

    // LDS: [0,16K) Q stage -> reused as Of [64 c][128 t] f32 swizzled [0,32K);
    //      [32K, 33K) Lbuf[2][128]; [33K, 33.5K) Linv[128]
    __shared__ __align__(16) char lds[34 * 1024];
    float* Lbuf = (float*)(lds + 32 * 1024);
    float* Linv = (float*)(lds + 33 * 1024);

    // stage Q tile (16 KB) linearly; content is pre-swizzled
    #pragma unroll
    for (int i = 0; i < 4; ++i)
        gload16(Qb + tid * 16 + i * 4096, lds + tid * 16 + i * 4096);
    asm volatile("s_waitcnt vmcnt(0)");
    __syncthreads();

    // hoist Q fragments for both t-sub-halves: B operand, n=t=wt*64+th*32+ll5
    bf16x8 qf0[4], qf1[4];
    #pragma unroll
    for (int kc = 0; kc < 4; ++kc) {
        qf0[kc] = *(const bf16x8*)(lds + swzK(wt * 64 + ll5,      kc * 32 + hi * 16));
        qf1[kc] = *(const bf16x8*)(lds + swzK(wt * 64 + 32 + ll5, kc * 32 + hi * 16));
    }

    const int voff = hi * 512 + ll5 * 16;      // per-lane offset within a frag block
    const int sbeg = wp * 16;                  // this wave's s-tile range

    // prologue: K fragments of first tile
    bf16x8 kf0[4], kf1[4];
    {
        const char* Kt = Kb + (size_t)sbeg * 8192 + voff;
        #pragma unroll
        for (int kc = 0; kc < 4; ++kc) {
            kf0[kc] = *(const bf16x8*)(Kt + kc * 2048);
            kf1[kc] = *(const bf16x8*)(Kt + kc * 2048 + 1024);
        }
    }

    f32x16 o00 = {}, o01 = {}, o10 = {}, o11 = {};
    float l0 = 0.f, l1 = 0.f;

    #pragma unroll 1
    for (int i = 0; i < 16; ++i) {
        const int ti = sbeg + i;

        // issue V(ti) fragment loads (consumed at end of iteration)
        bf16x8 vf0[4], vf1[4];
        {
            const char* Vt = Vb + (size_t)ti * 8192 + voff;
            #pragma unroll
            for (int ks = 0; ks < 4; ++ks) {
                vf0[ks] = *(const bf16x8*)(Vt + ks * 2048);
                vf1[ks] = *(const bf16x8*)(Vt + ks * 2048 + 1024);
            }
        }

        // ---- QK t-half0: S[s][t], A=K frag (m=s), B=Q frag (n=t) ----
        f32x16 sa = {}, sb = {};
        #pragma unroll
        for (int kc = 0; kc < 4; ++kc) {
            sa = __builtin_amdgcn_mfma_f32_32x32x16_bf16(kf0[kc], qf0[kc], sa, 0, 0, 0);
            sb = __builtin_amdgcn_mfma_f32_32x32x16_bf16(kf1[kc], qf0[kc], sb, 0, 0, 0);
        }
        bf16x8 pa0[4];
        expcvt(sa, sb, l0, pa0);

        // ---- QK t-half1 ----
        f32x16 sc = {}, sd = {};
        #pragma unroll
        for (int kc = 0; kc < 4; ++kc) {
            sc = __builtin_amdgcn_mfma_f32_32x32x16_bf16(kf0[kc], qf1[kc], sc, 0, 0, 0);
            sd = __builtin_amdgcn_mfma_f32_32x32x16_bf16(kf1[kc], qf1[kc], sd, 0, 0, 0);
        }

        // prefetch K(next) fragments (K frags now dead; exp+PV slack covers L2 hit)
        if (i != 15) {
            const char* Kt = Kb + (size_t)(ti + 1) * 8192 + voff;
            #pragma unroll
            for (int kc = 0; kc < 4; ++kc) {
                kf0[kc] = *(const bf16x8*)(Kt + kc * 2048);
                kf1[kc] = *(const bf16x8*)(Kt + kc * 2048 + 1024);
            }
        }

        bf16x8 pa1[4];
        expcvt(sc, sd, l1, pa1);

        // ---- O += P@V: A=pa (m=t), B=V frag (n=c) ----
        #pragma unroll
        for (int ks = 0; ks < 4; ++ks) {
            o00 = __builtin_amdgcn_mfma_f32_32x32x16_bf16(pa0[ks], vf0[ks], o00, 0, 0, 0);
            o01 = __builtin_amdgcn_mfma_f32_32x32x16_bf16(pa0[ks], vf1[ks], o01, 0, 0, 0);
            o10 = __builtin_amdgcn_mfma_f32_32x32x16_bf16(pa1[ks], vf0[ks], o10, 0, 0, 0);
            o11 = __builtin_amdgcn_mfma_f32_32x32x16_bf16(pa1[ks], vf1[ks], o11, 0, 0, 0);
        }
    }

    // ---- epilogue: combine s-halves, normalize at store ----
    // partial row-sums: lf0 valid for t = wt*64+ll5, lf1 for +32
    const float lf0 = l0 + __shfl_xor(l0, 32);
    const float lf1 = l1 + __shfl_xor(l1, 32);
    if (lane < 32) {
        Lbuf[wp * 128 + wt * 64 + ll5]      = lf0;
        Lbuf[wp * 128 + wt * 64 + 32 + ll5] = lf1;
    }
    __syncthreads();            // also: all waves past Q-LDS reads; Of writable
    if (tid < 128) Linv[tid] = 1.0f / (Lbuf[tid] + Lbuf[128 + tid]);

    float* Of = (float*)lds;    // [64 c][128 t] f32, swizzled (overlaps dead Q)
    #pragma unroll
    for (int ph = 0; ph < 2; ++ph) {
        if (wp == ph) {
            #pragma unroll
            for (int th = 0; th < 2; ++th) {
                const f32x16& v0 = th ? o10 : o00;
                const f32x16& v1 = th ? o11 : o01;
                #pragma unroll
                for (int jj = 0; jj < 4; ++jj) {
                    const int tb = wt * 64 + th * 32 + 8 * jj + 4 * hi;
                    f32x4 u0, u1;
                    #pragma unroll
                    for (int r = 0; r < 4; ++r) { u0[r] = v0[4 * jj + r]; u1[r] = v1[4 * jj + r]; }
                    char* p0 = (char*)Of + swzO(ll5,      tb * 4);
                    char* p1 = (char*)Of + swzO(32 + ll5, tb * 4);
                    if (ph == 0) {
                        *(f32x4*)p0 = u0;
                        *(f32x4*)p1 = u1;
                    } else {
                        *(f32x4*)p0 = *(f32x4*)p0 + u0;
                        *(f32x4*)p1 = *(f32x4*)p1 + u1;
                    }
                }
            }
        }
        __syncthreads();
    }

    float* op = out + (size_t)head * DCH * NLEN + t0;
    #pragma unroll
    for (int ch = 0; ch < 8; ++ch) {
        const int idx = tid + ch * 256;     // 0..2047
        const int c = idx >> 5, tq = idx & 31;
        f32x4 v  = *(const f32x4*)((char*)Of + swzO(c, tq * 16));
        f32x4 li = *(const f32x4*)&Linv[tq * 4];
        v = v * li;
        *(float4*)(op + (size_t)c * NLEN + tq * 4) = *(float4*)&v;
    }
}

// ---------------- fallback (R2 kernel) if ws is too small ----------------
#define QSCALE_FB 0.35355339059327373f
__global__ __launch_bounds__(512, 2)
void attn_fwd(const float* __restrict__ qkv, float* __restrict__ out)
{
    const int tid  = threadIdx.x;
    const int lane = tid & 63;
    const int w    = tid >> 6;
    const int lg   = lane >> 4;
    const int ll   = lane & 15;
    const int tblk = blockIdx.x;
    const int head = blockIdx.y;
    const int t0   = tblk * 128;

    const float* qp = qkv + (size_t)head * (3 * DCH) * NLEN;
    const float* kp = qp + (size_t)DCH * NLEN;
    const float* vp = kp + (size_t)DCH * NLEN;

    __shared__ __align__(16) char lds[48 * 1024];
    char* Qs = lds;
    char* Ks = lds + 16 * 1024;
    char* Vs = lds + 24 * 1024;
    char* Ps = lds + 32 * 1024 + w * 2048;

    {
        const int G = tid >> 6;
        #pragma unroll
        for (int it = 0; it < 2; ++it) {
            const int t = (tid & 63) + it * 64;
            const float* src = qp + (size_t)(G * 8) * NLEN + t0 + t;
            bf16 tmp[8];
            #pragma unroll
            for (int j = 0; j < 8; ++j) tmp[j] = (bf16)(src[(size_t)j * NLEN] * QSCALE_FB);
            *(bf16x8*)(Qs + swzK(t, G * 16)) = *(bf16x8*)tmp;
        }
    }
    __syncthreads();
    bf16x8 qf[2];
    #pragma unroll
    for (int kk = 0; kk < 2; ++kk)
        qf[kk] = *(const bf16x8*)(Qs + swzK(w * 16 + ll, kk * 64 + lg * 16));

    f32x4 o[4] = {};
    float m_r = -3.0e38f, l_r = 0.f;

    for (int sb = 0; sb < NLEN / 64; ++sb) {
        const int s0 = sb * 64;
        __syncthreads();
        {
            const int s = tid & 63, G = tid >> 6;
            const float* src = kp + (size_t)(G * 8) * NLEN + s0 + s;
            bf16 tmp[8];
            #pragma unroll
            for (int j = 0; j < 8; ++j) tmp[j] = (bf16)(src[(size_t)j * NLEN] * QSCALE_FB);
            *(bf16x8*)(Ks + swzK(s, G * 16)) = *(bf16x8*)tmp;
        }
        {
            const int c = tid >> 3, s8 = tid & 7;
            const float* src = vp + (size_t)c * NLEN + s0 + s8 * 8;
            const float4 f0 = *(const float4*)src;
            const float4 f1 = *(const float4*)(src + 4);
            bf16 tmp[8] = {(bf16)f0.x, (bf16)f0.y, (bf16)f0.z, (bf16)f0.w,
                           (bf16)f1.x, (bf16)f1.y, (bf16)f1.z, (bf16)f1.w};
            *(bf16x8*)(Vs + swzK(c, s8 * 16)) = *(bf16x8*)tmp;
        }
        __syncthreads();

        f32x4 sf[4] = {};
        #pragma unroll
        for (int kk = 0; kk < 2; ++kk)
            #pragma unroll
            for (int fs = 0; fs < 4; ++fs) {
                bf16x8 a = *(const bf16x8*)(Ks + swzK(fs * 16 + ll, kk * 64 + lg * 16));
                sf[fs] = __builtin_amdgcn_mfma_f32_16x16x32_bf16(a, qf[kk], sf[fs], 0, 0, 0);
            }

        float mx;
        {
            f32x4 m4 = sf[0];
            #pragma unroll
            for (int fs = 1; fs < 4; ++fs) {
                m4[0] = fmaxf(m4[0], sf[fs][0]); m4[1] = fmaxf(m4[1], sf[fs][1]);
                m4[2] = fmaxf(m4[2], sf[fs][2]); m4[3] = fmaxf(m4[3], sf[fs][3]);
            }
            mx = fmaxf(fmaxf(m4[0], m4[1]), fmaxf(m4[2], m4[3]));
        }
        mx = fmaxf(mx, __shfl_xor(mx, 16));
        mx = fmaxf(mx, __shfl_xor(mx, 32));
        const float mnew = fmaxf(m_r, mx);
        const float corr = exp2f((m_r - mnew) * 1.4426950408889634f);
        m_r = mnew;
        const float cm = mnew * 1.4426950408889634f;

        float psum = 0.f;
        #pragma unroll
        for (int fs = 0; fs < 4; ++fs) {
            bf16x4 pw;
            #pragma unroll
            for (int r = 0; r < 4; ++r) {
                float p = exp2f(fmaf(sf[fs][r], 1.4426950408889634f, -cm));
                psum += p;
                pw[r] = (bf16)p;
            }
            *(bf16x4*)(Ps + swzK(ll, 32 * fs + 8 * lg)) = pw;
        }
        psum += __shfl_xor(psum, 16);
        psum += __shfl_xor(psum, 32);
        l_r = l_r * corr + psum;

        float corr4[4];
        #pragma unroll
        for (int r = 0; r < 4; ++r) corr4[r] = __shfl(corr, 4 * lg + r);
        #pragma unroll
        for (int cf = 0; cf < 4; ++cf)
            #pragma unroll
            for (int r = 0; r < 4; ++r) o[cf][r] *= corr4[r];

        #pragma unroll
        for (int kk = 0; kk < 2; ++kk) {
            bf16x8 pa = *(const bf16x8*)(Ps + swzK(ll, kk * 64 + lg * 16));
            #pragma unroll
            for (int cf = 0; cf < 4; ++cf) {
                bf16x8 b = *(const bf16x8*)(Vs + swzK(cf * 16 + ll, kk * 64 + lg * 16));
                o[cf] = __builtin_amdgcn_mfma_f32_16x16x32_bf16(pa, b, o[cf], 0, 0, 0);
            }
        }
    }

    __syncthreads();
    const float linv = 1.0f / l_r;
    float linv4[4];
    #pragma unroll
    for (int r = 0; r < 4; ++r) linv4[r] = __shfl(linv, 4 * lg + r);
    float* Of = (float*)lds;
    #pragma unroll
    for (int cf = 0; cf < 4; ++cf) {
        f32x4 ov;
        #pragma unroll
        for (int r = 0; r < 4; ++r) ov[r] = o[cf][r] * linv4[r];
        *(f32x4*)((char*)Of + swzO(cf * 16 + ll, (w * 16 + 4 * lg) * 4)) = ov;
    }
    __syncthreads();
    float* op = out + (size_t)head * DCH * NLEN + t0;
    #pragma unroll
    for (int it = 0; it < 4; ++it) {
        const int idx = tid + it * 512;
        const int c = idx >> 5, tq = idx & 31;
        f32x4 v = *(const f32x4*)((char*)Of + swzO(c, tq * 16));
        *(float4*)(op + (size_t)c * NLEN + tq * 4) = *(float4*)&v;
    }
}

extern "C" void kernel_launch(void* const* d_in, const int* in_sizes, int n_in,
                              void* d_out, int out_size, void* d_ws, size_t ws_size,
                              hipStream_t stream)
{
    const float* qkv = (const float*)d_in[0];
    float* out = (float*)d_out;
    if (ws_size >= (size_t)WS_NEED) {
        char* ws = (char*)d_ws;
        prep<<<dim3(32, 64, 3), 256, 0, stream>>>(qkv, ws);
        attn_main<<<dim3(1024), 256, 0, stream>>>(ws, out);
    } else {
        attn_fwd<<<dim3(16, 64), 512, 0, stream>>>(qkv, out);
    }
}

// Round 10
// 235.931 us; speedup vs baseline: 2.8642x; 2.8642x over previous
//
#include <hip/hip_runtime.h>

// QKVAttentionLegacy on MI355X. qkv f32 (8,1536,2048) = 64 heads x [192][2048]:
// q rows 0:64, k 64:128, v 128:192, channel-major [c][pos].
// out[head][c][t] = sum_s softmax_s(qk/8)[t][s] v[c][s].
// R10: R9's s-split occupancy plan with register-pressure discipline.
//  - __launch_bounds__(256,3): VGPR cap ~170 -> allocator fits (R9's (256,4)
//    cap=128 collapsed to 64 VGPR + scratch spills -> 1.3GB fetch, 8x slower).
//  - V fragments loaded AT USE in PV (drops 32 long-lived VGPRs; L1-hit, TLP
//    covers latency). K(i+1) prefetch kept.
//  - WG = 4 waves: wt = t-half (64 rows), wp = s-half (16 tiles); partial O
//    merged via LDS RMW, l via LDS buffer, normalize at store (fixed-shift
//    softmax => order-independent summation).
// Kept: prep -> bf16 frag-major K/V + pre-swizzled Q (exp scale folded),
// direct-from-global MFMA operands, barrier-free s-loop, 32x32x16 MFMA,
// in-register P via cvt_pk+permlane32_swap, native v_exp, no setprio.

typedef __bf16 bf16;
typedef __bf16 bf16x4 __attribute__((ext_vector_type(4)));
typedef __bf16 bf16x8 __attribute__((ext_vector_type(8)));
typedef float  f32x4  __attribute__((ext_vector_type(4)));
typedef float  f32x16 __attribute__((ext_vector_type(16)));
typedef unsigned int u32;

#define NLEN 2048
#define DCH  64
#define HSTR (NLEN * DCH * 2)          // 256 KB per head per array (bytes)
#define WS_K (16u * 1024u * 1024u)
#define WS_V (32u * 1024u * 1024u)
#define WS_NEED (48u * 1024u * 1024u)
// sqrt(0.125 * log2(e)) -- q,k each scaled by this in prep, so S = (qk/8)*log2e
#define PSCALE 0.42466119f

// 128-byte rows, 16B-granule XOR swizzle (involution): G' = G ^ (row&7)  [Q only]
__device__ __forceinline__ int swzK(int row, int cb) {
    return row * 128 + ((((cb >> 4) ^ row) & 7) << 4) + (cb & 15);
}
// 512-byte f32 rows for the output transpose buffer
__device__ __forceinline__ int swzO(int row, int cb) {
    int g = cb >> 4;
    g = (g & ~7) | ((g ^ row) & 7);
    return row * 512 + (g << 4) + (cb & 15);
}

__device__ __forceinline__ void gload16(const char* g, char* l) {
    __builtin_amdgcn_global_load_lds((const __attribute__((address_space(1))) void*)g,
                                     (__attribute__((address_space(3))) void*)l, 16, 0, 0);
}

// ---------------- prep ----------------
// Q: bf16 scaled, transposed [t][c], XOR-pre-swizzled (consumed via LDS once).
// K: bf16 scaled, frag-major per 64-s tile: [kc:4][rh:2][hi:2][ll5:32][8 bf16]
//    holding K[s = rh*32+ll5][c = kc*16+hi*8+b]  (A-operand of QK, coalesced).
// V: bf16 unscaled, frag-major per 64-s tile: [ks:4][rh:2][hi:2][ll5:32][8 bf16]
//    holding V[c = rh*32+ll5][s = ks*16+hi*8+b]  (B-operand of PV, coalesced).
__global__ __launch_bounds__(256)
void prep(const float* __restrict__ qkv, char* __restrict__ ws)
{
    const int tid  = threadIdx.x;
    const int pb   = blockIdx.x;    // 64-pos block (0..31)
    const int head = blockIdx.y;    // 0..63
    const int type = blockIdx.z;    // 0=q 1=k 2=v

    const float* src = qkv + (size_t)head * (3 * DCH) * NLEN + (size_t)type * DCH * NLEN;
    char* dst = ws + (type == 0 ? 0u : (type == 1 ? WS_K : WS_V))
                   + (size_t)head * HSTR + (size_t)pb * 8192;

    if (type < 2) {
        __shared__ float T[64][65];   // [pos][c], +1 pad
        #pragma unroll
        for (int p = 0; p < 4; ++p) {
            int idx = tid + p * 256;
            int c = idx >> 4, q4 = idx & 15;
            float4 f = *(const float4*)(src + (size_t)c * NLEN + pb * 64 + q4 * 4);
            T[q4 * 4 + 0][c] = f.x * PSCALE;
            T[q4 * 4 + 1][c] = f.y * PSCALE;
            T[q4 * 4 + 2][c] = f.z * PSCALE;
            T[q4 * 4 + 3][c] = f.w * PSCALE;
        }
        __syncthreads();
        #pragma unroll
        for (int p = 0; p < 2; ++p) {
            int gidx = tid + p * 256;
            int s = gidx >> 3, G = gidx & 7;
            if (type == 0) {
                int c0 = (G ^ (s & 7)) * 8;          // pre-swizzled [t][c]
                bf16 tmp[8];
                #pragma unroll
                for (int j = 0; j < 8; ++j) tmp[j] = (bf16)T[s][c0 + j];
                *(bf16x8*)(dst + s * 128 + G * 16) = *(bf16x8*)tmp;
            } else {
                // frag-major K: c-elems G*8..G*8+7 of row s
                const int kc = G >> 1, hi = G & 1;
                bf16 tmp[8];
                #pragma unroll
                for (int j = 0; j < 8; ++j) tmp[j] = (bf16)T[s][G * 8 + j];
                *(bf16x8*)(dst + kc * 2048 + ((s >> 5) & 1) * 1024 + hi * 512
                               + (s & 31) * 16) = *(bf16x8*)tmp;
            }
        }
    } else {
        const int c = tid >> 2, m = tid & 3;      // m = ks
        const float* sp = src + (size_t)c * NLEN + pb * 64 + m * 16;
        float f[16];
        #pragma unroll
        for (int j = 0; j < 4; ++j) *(f32x4*)(f + 4 * j) = *(const f32x4*)(sp + 4 * j);
        #pragma unroll
        for (int gl = 0; gl < 2; ++gl) {          // gl = hi
            bf16 tmp[8];
            #pragma unroll
            for (int j = 0; j < 8; ++j) tmp[j] = (bf16)f[gl * 8 + j];
            *(bf16x8*)(dst + m * 2048 + ((c >> 5) & 1) * 1024 + gl * 512
                           + (c & 31) * 16) = *(bf16x8*)tmp;
        }
    }
}

// exp2 + l-sum + cvt_pk/permlane32_swap: S-half (rows 0-31 = slo, 32-63 = shi,
// one t-half) -> A-operand fragments pa[0..3]
__device__ __forceinline__ void expcvt(f32x16& slo, f32x16& shi, float& l, bf16x8 pa[4])
{
    float a = 0.f, b = 0.f, c = 0.f, d = 0.f;
    #pragma unroll
    for (int r = 0; r < 16; r += 4) {
        slo[r+0] = __builtin_amdgcn_exp2f(slo[r+0]); a += slo[r+0];
        slo[r+1] = __builtin_amdgcn_exp2f(slo[r+1]); b += slo[r+1];
        slo[r+2] = __builtin_amdgcn_exp2f(slo[r+2]); c += slo[r+2];
        slo[r+3] = __builtin_amdgcn_exp2f(slo[r+3]); d += slo[r+3];
    }
    #pragma unroll
    for (int r = 0; r < 16; r += 4) {
        shi[r+0] = __builtin_amdgcn_exp2f(shi[r+0]); a += shi[r+0];
        shi[r+1] = __builtin_amdgcn_exp2f(shi[r+1]); b += shi[r+1];
        shi[r+2] = __builtin_amdgcn_exp2f(shi[r+2]); c += shi[r+2];
        shi[r+3] = __builtin_amdgcn_exp2f(shi[r+3]); d += shi[r+3];
    }
    l += (a + b) + (c + d);
    #pragma unroll
    for (int ks = 0; ks < 4; ++ks) {
        const f32x16& pp = (ks < 2) ? slo : shi;
        const int rb = (ks & 1) * 8;
        u32 X, X2, Y, Y2;
        asm("v_cvt_pk_bf16_f32 %0, %1, %2" : "=v"(X)  : "v"(pp[rb + 0]), "v"(pp[rb + 1]));
        asm("v_cvt_pk_bf16_f32 %0, %1, %2" : "=v"(X2) : "v"(pp[rb + 2]), "v"(pp[rb + 3]));
        asm("v_cvt_pk_bf16_f32 %0, %1, %2" : "=v"(Y)  : "v"(pp[rb + 4]), "v"(pp[rb + 5]));
        asm("v_cvt_pk_bf16_f32 %0, %1, %2" : "=v"(Y2) : "v"(pp[rb + 6]), "v"(pp[rb + 7]));
        asm("v_permlane32_swap_b32 %0, %1" : "+v"(X),  "+v"(Y));
        asm("v_permlane32_swap_b32 %0, %1" : "+v"(X2), "+v"(Y2));
        u32 wds[4] = {X, X2, Y, Y2};
        pa[ks] = *(bf16x8*)wds;
    }
}

// ---------------- main: 128 t/WG, 4 waves (2 t-halves x 2 s-halves) ----------------
__global__ __launch_bounds__(256, 3)
void attn_main(const char* __restrict__ ws, float* __restrict__ out)
{
    const int tid  = threadIdx.x;
    const int lane = tid & 63;
    const int w    = tid >> 6;     // wave 0..3
    const int wt   = w & 1;        // t-half: rows [wt*64, wt*64+64)
    const int wp   = w >> 1;       // s-half: tiles [wp*16, wp*16+16)
    const int hi   = lane >> 5;
    const int ll5  = lane & 31;

    // bid&7 = XCD (round-robin dispatch). Per XCD: j in 0..127; co-resident WGs
    // (j, j+32, j+64, j+96) share a head -> K/V tiles are L1/L2 temporal hits.
    const int bid  = blockIdx.x;
    const int j    = bid >> 3;
    const int head = (bid & 7) * 8 + (j & 7);
    const int tblk = j >> 3;       // 0..15
    const int t0   = tblk * 128;

    const char* Qb = ws + (size_t)head * HSTR + (size_t)t0 * 128;
    const char* Kb = ws + WS_K + (size_t)head * HSTR;
    const char* Vb = ws + WS_V + (size_t)head * HSTR;

    // LDS: [0,16K) Q stage -> reused as Of [64 c][128 t] f32 swizzled [0,32K);
    //      [32K, 33K) Lbuf[2][128]; [33K, 33.5K) Linv[128]
    __shared__ __align__(16) char lds[34 * 1024];
    float* Lbuf = (float*)(lds + 32 * 1024);
    float* Linv = (float*)(lds + 33 * 1024);

    // stage Q tile (16 KB) linearly; content is pre-swizzled
    #pragma unroll
    for (int i = 0; i < 4; ++i)
        gload16(Qb + tid * 16 + i * 4096, lds + tid * 16 + i * 4096);
    asm volatile("s_waitcnt vmcnt(0)");
    __syncthreads();

    // hoist Q fragments for both t-sub-halves: B operand, n=t=wt*64+th*32+ll5
    bf16x8 qf0[4], qf1[4];
    #pragma unroll
    for (int kc = 0; kc < 4; ++kc) {
        qf0[kc] = *(const bf16x8*)(lds + swzK(wt * 64 + ll5,      kc * 32 + hi * 16));
        qf1[kc] = *(const bf16x8*)(lds + swzK(wt * 64 + 32 + ll5, kc * 32 + hi * 16));
    }

    const int voff = hi * 512 + ll5 * 16;      // per-lane offset within a frag block
    const int sbeg = wp * 16;                  // this wave's s-tile range

    // prologue: K fragments of first tile
    bf16x8 kf0[4], kf1[4];
    {
        const char* Kt = Kb + (size_t)sbeg * 8192 + voff;
        #pragma unroll
        for (int kc = 0; kc < 4; ++kc) {
            kf0[kc] = *(const bf16x8*)(Kt + kc * 2048);
            kf1[kc] = *(const bf16x8*)(Kt + kc * 2048 + 1024);
        }
    }

    f32x16 o00 = {}, o01 = {}, o10 = {}, o11 = {};
    float l0 = 0.f, l1 = 0.f;

    #pragma unroll 1
    for (int i = 0; i < 16; ++i) {
        const int ti = sbeg + i;
        const char* Vt = Vb + (size_t)ti * 8192 + voff;

        // ---- QK t-half0: S[s][t], A=K frag (m=s), B=Q frag (n=t) ----
        f32x16 sa = {}, sb = {};
        #pragma unroll
        for (int kc = 0; kc < 4; ++kc) {
            sa = __builtin_amdgcn_mfma_f32_32x32x16_bf16(kf0[kc], qf0[kc], sa, 0, 0, 0);
            sb = __builtin_amdgcn_mfma_f32_32x32x16_bf16(kf1[kc], qf0[kc], sb, 0, 0, 0);
        }
        bf16x8 pa0[4];
        expcvt(sa, sb, l0, pa0);

        // ---- QK t-half1 ----
        f32x16 sc = {}, sd = {};
        #pragma unroll
        for (int kc = 0; kc < 4; ++kc) {
            sc = __builtin_amdgcn_mfma_f32_32x32x16_bf16(kf0[kc], qf1[kc], sc, 0, 0, 0);
            sd = __builtin_amdgcn_mfma_f32_32x32x16_bf16(kf1[kc], qf1[kc], sd, 0, 0, 0);
        }

        // prefetch K(next) fragments (K frags now dead; exp+PV slack covers hit)
        if (i != 15) {
            const char* Kt = Kb + (size_t)(ti + 1) * 8192 + voff;
            #pragma unroll
            for (int kc = 0; kc < 4; ++kc) {
                kf0[kc] = *(const bf16x8*)(Kt + kc * 2048);
                kf1[kc] = *(const bf16x8*)(Kt + kc * 2048 + 1024);
            }
        }

        bf16x8 pa1[4];
        expcvt(sc, sd, l1, pa1);

        // ---- O += P@V: A=pa (m=t), B=V frag (n=c); V loaded at use (L1 hit) ----
        #pragma unroll
        for (int ks = 0; ks < 4; ++ks) {
            bf16x8 b0 = *(const bf16x8*)(Vt + ks * 2048);
            bf16x8 b1 = *(const bf16x8*)(Vt + ks * 2048 + 1024);
            o00 = __builtin_amdgcn_mfma_f32_32x32x16_bf16(pa0[ks], b0, o00, 0, 0, 0);
            o01 = __builtin_amdgcn_mfma_f32_32x32x16_bf16(pa0[ks], b1, o01, 0, 0, 0);
            o10 = __builtin_amdgcn_mfma_f32_32x32x16_bf16(pa1[ks], b0, o10, 0, 0, 0);
            o11 = __builtin_amdgcn_mfma_f32_32x32x16_bf16(pa1[ks], b1, o11, 0, 0, 0);
        }
    }

    // ---- epilogue: combine s-halves, normalize at store ----
    const float lf0 = l0 + __shfl_xor(l0, 32);
    const float lf1 = l1 + __shfl_xor(l1, 32);
    if (lane < 32) {
        Lbuf[wp * 128 + wt * 64 + ll5]      = lf0;
        Lbuf[wp * 128 + wt * 64 + 32 + ll5] = lf1;
    }
    __syncthreads();            // also: all waves past Q-LDS reads; Of writable
    if (tid < 128) Linv[tid] = 1.0f / (Lbuf[tid] + Lbuf[128 + tid]);

    float* Of = (float*)lds;    // [64 c][128 t] f32, swizzled (overlaps dead Q)
    #pragma unroll
    for (int ph = 0; ph < 2; ++ph) {
        if (wp == ph) {
            #pragma unroll
            for (int th = 0; th < 2; ++th) {
                const f32x16& v0 = th ? o10 : o00;
                const f32x16& v1 = th ? o11 : o01;
                #pragma unroll
                for (int jj = 0; jj < 4; ++jj) {
                    const int tb = wt * 64 + th * 32 + 8 * jj + 4 * hi;
                    f32x4 u0, u1;
                    #pragma unroll
                    for (int r = 0; r < 4; ++r) { u0[r] = v0[4 * jj + r]; u1[r] = v1[4 * jj + r]; }
                    char* p0 = (char*)Of + swzO(ll5,      tb * 4);
                    char* p1 = (char*)Of + swzO(32 + ll5, tb * 4);
                    if (ph == 0) {
                        *(f32x4*)p0 = u0;
                        *(f32x4*)p1 = u1;
                    } else {
                        *(f32x4*)p0 = *(f32x4*)p0 + u0;
                        *(f32x4*)p1 = *(f32x4*)p1 + u1;
                    }
                }
            }
        }
        __syncthreads();
    }

    float* op = out + (size_t)head * DCH * NLEN + t0;
    #pragma unroll
    for (int ch = 0; ch < 8; ++ch) {
        const int idx = tid + ch * 256;     // 0..2047
        const int c = idx >> 5, tq = idx & 31;
        f32x4 v  = *(const f32x4*)((char*)Of + swzO(c, tq * 16));
        f32x4 li = *(const f32x4*)&Linv[tq * 4];
        v = v * li;
        *(float4*)(op + (size_t)c * NLEN + tq * 4) = *(float4*)&v;
    }
}

// ---------------- fallback (R2 kernel) if ws is too small ----------------
#define QSCALE_FB 0.35355339059327373f
__global__ __launch_bounds__(512, 2)
void attn_fwd(const float* __restrict__ qkv, float* __restrict__ out)
{
    const int tid  = threadIdx.x;
    const int lane = tid & 63;
    const int w    = tid >> 6;
    const int lg   = lane >> 4;
    const int ll   = lane & 15;
    const int tblk = blockIdx.x;
    const int head = blockIdx.y;
    const int t0   = tblk * 128;

    const float* qp = qkv + (size_t)head * (3 * DCH) * NLEN;
    const float* kp = qp + (size_t)DCH * NLEN;
    const float* vp = kp + (size_t)DCH * NLEN;

    __shared__ __align__(16) char lds[48 * 1024];
    char* Qs = lds;
    char* Ks = lds + 16 * 1024;
    char* Vs = lds + 24 * 1024;
    char* Ps = lds + 32 * 1024 + w * 2048;

    {
        const int G = tid >> 6;
        #pragma unroll
        for (int it = 0; it < 2; ++it) {
            const int t = (tid & 63) + it * 64;
            const float* src = qp + (size_t)(G * 8) * NLEN + t0 + t;
            bf16 tmp[8];
            #pragma unroll
            for (int j = 0; j < 8; ++j) tmp[j] = (bf16)(src[(size_t)j * NLEN] * QSCALE_FB);
            *(bf16x8*)(Qs + swzK(t, G * 16)) = *(bf16x8*)tmp;
        }
    }
    __syncthreads();
    bf16x8 qf[2];
    #pragma unroll
    for (int kk = 0; kk < 2; ++kk)
        qf[kk] = *(const bf16x8*)(Qs + swzK(w * 16 + ll, kk * 64 + lg * 16));

    f32x4 o[4] = {};
    float m_r = -3.0e38f, l_r = 0.f;

    for (int sb = 0; sb < NLEN / 64; ++sb) {
        const int s0 = sb * 64;
        __syncthreads();
        {
            const int s = tid & 63, G = tid >> 6;
            const float* src = kp + (size_t)(G * 8) * NLEN + s0 + s;
            bf16 tmp[8];
            #pragma unroll
            for (int j = 0; j < 8; ++j) tmp[j] = (bf16)(src[(size_t)j * NLEN] * QSCALE_FB);
            *(bf16x8*)(Ks + swzK(s, G * 16)) = *(bf16x8*)tmp;
        }
        {
            const int c = tid >> 3, s8 = tid & 7;
            const float* src = vp + (size_t)c * NLEN + s0 + s8 * 8;
            const float4 f0 = *(const float4*)src;
            const float4 f1 = *(const float4*)(src + 4);
            bf16 tmp[8] = {(bf16)f0.x, (bf16)f0.y, (bf16)f0.z, (bf16)f0.w,
                           (bf16)f1.x, (bf16)f1.y, (bf16)f1.z, (bf16)f1.w};
            *(bf16x8*)(Vs + swzK(c, s8 * 16)) = *(bf16x8*)tmp;
        }
        __syncthreads();

        f32x4 sf[4] = {};
        #pragma unroll
        for (int kk = 0; kk < 2; ++kk)
            #pragma unroll
            for (int fs = 0; fs < 4; ++fs) {
                bf16x8 a = *(const bf16x8*)(Ks + swzK(fs * 16 + ll, kk * 64 + lg * 16));
                sf[fs] = __builtin_amdgcn_mfma_f32_16x16x32_bf16(a, qf[kk], sf[fs], 0, 0, 0);
            }

        float mx;
        {
            f32x4 m4 = sf[0];
            #pragma unroll
            for (int fs = 1; fs < 4; ++fs) {
                m4[0] = fmaxf(m4[0], sf[fs][0]); m4[1] = fmaxf(m4[1], sf[fs][1]);
                m4[2] = fmaxf(m4[2], sf[fs][2]); m4[3] = fmaxf(m4[3], sf[fs][3]);
            }
            mx = fmaxf(fmaxf(m4[0], m4[1]), fmaxf(m4[2], m4[3]));
        }
        mx = fmaxf(mx, __shfl_xor(mx, 16));
        mx = fmaxf(mx, __shfl_xor(mx, 32));
        const float mnew = fmaxf(m_r, mx);
        const float corr = exp2f((m_r - mnew) * 1.4426950408889634f);
        m_r = mnew;
        const float cm = mnew * 1.4426950408889634f;

        float psum = 0.f;
        #pragma unroll
        for (int fs = 0; fs < 4; ++fs) {
            bf16x4 pw;
            #pragma unroll
            for (int r = 0; r < 4; ++r) {
                float p = exp2f(fmaf(sf[fs][r], 1.4426950408889634f, -cm));
                psum += p;
                pw[r] = (bf16)p;
            }
            *(bf16x4*)(Ps + swzK(ll, 32 * fs + 8 * lg)) = pw;
        }
        psum += __shfl_xor(psum, 16);
        psum += __shfl_xor(psum, 32);
        l_r = l_r * corr + psum;

        float corr4[4];
        #pragma unroll
        for (int r = 0; r < 4; ++r) corr4[r] = __shfl(corr, 4 * lg + r);
        #pragma unroll
        for (int cf = 0; cf < 4; ++cf)
            #pragma unroll
            for (int r = 0; r < 4; ++r) o[cf][r] *= corr4[r];

        #pragma unroll
        for (int kk = 0; kk < 2; ++kk) {
            bf16x8 pa = *(const bf16x8*)(Ps + swzK(ll, kk * 64 + lg * 16));
            #pragma unroll
            for (int cf = 0; cf < 4; ++cf) {
                bf16x8 b = *(const bf16x8*)(Vs + swzK(cf * 16 + ll, kk * 64 + lg * 16));
                o[cf] = __builtin_amdgcn_mfma_f32_16x16x32_bf16(pa, b, o[cf], 0, 0, 0);
            }
        }
    }

    __syncthreads();
    const float linv = 1.0f / l_r;
    float linv4[4];
    #pragma unroll
    for (int r = 0; r < 4; ++r) linv4[r] = __shfl(linv, 4 * lg + r);
    float* Of = (float*)lds;
    #pragma unroll
    for (int cf = 0; cf < 4; ++cf) {
        f32x4 ov;
        #pragma unroll
        for (int r = 0; r < 4; ++r) ov[r] = o[cf][r] * linv4[r];
        *(f32x4*)((char*)Of + swzO(cf * 16 + ll, (w * 16 + 4 * lg) * 4)) = ov;
    }
    __syncthreads();
    float* op = out + (size_t)head * DCH * NLEN + t0;
    #pragma unroll
    for (int it = 0; it < 4; ++it) {
        const int idx = tid + it * 512;
        const int c = idx >> 5, tq = idx & 31;
        f32x4 v = *(const f32x4*)((char*)Of + swzO(c, tq * 16));
        *(float4*)(op + (size_t)c * NLEN + tq * 4) = *(float4*)&v;
    }
}

extern "C" void kernel_launch(void* const* d_in, const int* in_sizes, int n_in,
                              void* d_out, int out_size, void* d_ws, size_t ws_size,
                              hipStream_t stream)
{
    const float* qkv = (const float*)d_in[0];
    float* out = (float*)d_out;
    if (ws_size >= (size_t)WS_NEED) {
        char* ws = (char*)d_ws;
        prep<<<dim3(32, 64, 3), 256, 0, stream>>>(qkv, ws);
        attn_main<<<dim3(1024), 256, 0, stream>>>(ws, out);
    } else {
        attn_fwd<<<dim3(16, 64), 512, 0, stream>>>(qkv, out);
    }
}

// Round 11
// 113.349 us; speedup vs baseline: 5.9618x; 2.0815x over previous
//
#include <hip/hip_runtime.h>

// QKVAttentionLegacy on MI355X. qkv f32 (8,1536,2048) = 64 heads x [192][2048]:
// q rows 0:64, k 64:128, v 128:192, channel-major [c][pos].
// out[head][c][t] = sum_s softmax_s(qk/8)[t][s] v[c][s].
// R11: 32 t-rows/wave so the live-set honestly fits the 128-VGPR / 4-waves-per-
// SIMD tier (R9/R10: the 64-t loop needs ~128-180 live VGPRs; any launch-bounds
// demand above 2 waves/SIMD collapsed the allocator to 64-84 VGPR + GB-scale
// scratch spills). WG = 4 waves x 32 t = 128 t-block; grid 1024 -> 16 waves/CU.
// K and V fragments loaded AT USE (no long-lived prefetch) to cap the peak;
// 16 waves/CU of TLP cover the L1/L2 hit latency.
// Kept: prep -> bf16 frag-major K/V + pre-swizzled Q (exp scale folded),
// direct-from-global MFMA operands, barrier-free s-loop, 32x32x16 MFMA,
// in-register P via cvt_pk+permlane32_swap, native v_exp, same-head CU packing.

typedef __bf16 bf16;
typedef __bf16 bf16x4 __attribute__((ext_vector_type(4)));
typedef __bf16 bf16x8 __attribute__((ext_vector_type(8)));
typedef float  f32x4  __attribute__((ext_vector_type(4)));
typedef float  f32x16 __attribute__((ext_vector_type(16)));
typedef unsigned int u32;

#define NLEN 2048
#define DCH  64
#define HSTR (NLEN * DCH * 2)          // 256 KB per head per array (bytes)
#define WS_K (16u * 1024u * 1024u)
#define WS_V (32u * 1024u * 1024u)
#define WS_NEED (48u * 1024u * 1024u)
// sqrt(0.125 * log2(e)) -- q,k each scaled by this in prep, so S = (qk/8)*log2e
#define PSCALE 0.42466119f

// 128-byte rows, 16B-granule XOR swizzle (involution): G' = G ^ (row&7)  [Q only]
__device__ __forceinline__ int swzK(int row, int cb) {
    return row * 128 + ((((cb >> 4) ^ row) & 7) << 4) + (cb & 15);
}
// 512-byte f32 rows for the output transpose buffer
__device__ __forceinline__ int swzO(int row, int cb) {
    int g = cb >> 4;
    g = (g & ~7) | ((g ^ row) & 7);
    return row * 512 + (g << 4) + (cb & 15);
}

__device__ __forceinline__ void gload16(const char* g, char* l) {
    __builtin_amdgcn_global_load_lds((const __attribute__((address_space(1))) void*)g,
                                     (__attribute__((address_space(3))) void*)l, 16, 0, 0);
}

// ---------------- prep ----------------
// Q: bf16 scaled, transposed [t][c], XOR-pre-swizzled (consumed via LDS once).
// K: bf16 scaled, frag-major per 64-s tile: [kc:4][rh:2][hi:2][ll5:32][8 bf16]
//    holding K[s = rh*32+ll5][c = kc*16+hi*8+b]  (A-operand of QK, coalesced).
// V: bf16 unscaled, frag-major per 64-s tile: [ks:4][rh:2][hi:2][ll5:32][8 bf16]
//    holding V[c = rh*32+ll5][s = ks*16+hi*8+b]  (B-operand of PV, coalesced).
__global__ __launch_bounds__(256)
void prep(const float* __restrict__ qkv, char* __restrict__ ws)
{
    const int tid  = threadIdx.x;
    const int pb   = blockIdx.x;    // 64-pos block (0..31)
    const int head = blockIdx.y;    // 0..63
    const int type = blockIdx.z;    // 0=q 1=k 2=v

    const float* src = qkv + (size_t)head * (3 * DCH) * NLEN + (size_t)type * DCH * NLEN;
    char* dst = ws + (type == 0 ? 0u : (type == 1 ? WS_K : WS_V))
                   + (size_t)head * HSTR + (size_t)pb * 8192;

    if (type < 2) {
        __shared__ float T[64][65];   // [pos][c], +1 pad
        #pragma unroll
        for (int p = 0; p < 4; ++p) {
            int idx = tid + p * 256;
            int c = idx >> 4, q4 = idx & 15;
            float4 f = *(const float4*)(src + (size_t)c * NLEN + pb * 64 + q4 * 4);
            T[q4 * 4 + 0][c] = f.x * PSCALE;
            T[q4 * 4 + 1][c] = f.y * PSCALE;
            T[q4 * 4 + 2][c] = f.z * PSCALE;
            T[q4 * 4 + 3][c] = f.w * PSCALE;
        }
        __syncthreads();
        #pragma unroll
        for (int p = 0; p < 2; ++p) {
            int gidx = tid + p * 256;
            int s = gidx >> 3, G = gidx & 7;
            if (type == 0) {
                int c0 = (G ^ (s & 7)) * 8;          // pre-swizzled [t][c]
                bf16 tmp[8];
                #pragma unroll
                for (int j = 0; j < 8; ++j) tmp[j] = (bf16)T[s][c0 + j];
                *(bf16x8*)(dst + s * 128 + G * 16) = *(bf16x8*)tmp;
            } else {
                // frag-major K: c-elems G*8..G*8+7 of row s
                const int kc = G >> 1, hi = G & 1;
                bf16 tmp[8];
                #pragma unroll
                for (int j = 0; j < 8; ++j) tmp[j] = (bf16)T[s][G * 8 + j];
                *(bf16x8*)(dst + kc * 2048 + ((s >> 5) & 1) * 1024 + hi * 512
                               + (s & 31) * 16) = *(bf16x8*)tmp;
            }
        }
    } else {
        const int c = tid >> 2, m = tid & 3;      // m = ks
        const float* sp = src + (size_t)c * NLEN + pb * 64 + m * 16;
        float f[16];
        #pragma unroll
        for (int j = 0; j < 4; ++j) *(f32x4*)(f + 4 * j) = *(const f32x4*)(sp + 4 * j);
        #pragma unroll
        for (int gl = 0; gl < 2; ++gl) {          // gl = hi
            bf16 tmp[8];
            #pragma unroll
            for (int j = 0; j < 8; ++j) tmp[j] = (bf16)f[gl * 8 + j];
            *(bf16x8*)(dst + m * 2048 + ((c >> 5) & 1) * 1024 + gl * 512
                           + (c & 31) * 16) = *(bf16x8*)tmp;
        }
    }
}

// exp2 + l-sum + cvt_pk/permlane32_swap: S (rows 0-31 = slo, 32-63 = shi) ->
// A-operand fragments pa[0..3]
__device__ __forceinline__ void expcvt(f32x16& slo, f32x16& shi, float& l, bf16x8 pa[4])
{
    float a = 0.f, b = 0.f, c = 0.f, d = 0.f;
    #pragma unroll
    for (int r = 0; r < 16; r += 4) {
        slo[r+0] = __builtin_amdgcn_exp2f(slo[r+0]); a += slo[r+0];
        slo[r+1] = __builtin_amdgcn_exp2f(slo[r+1]); b += slo[r+1];
        slo[r+2] = __builtin_amdgcn_exp2f(slo[r+2]); c += slo[r+2];
        slo[r+3] = __builtin_amdgcn_exp2f(slo[r+3]); d += slo[r+3];
    }
    #pragma unroll
    for (int r = 0; r < 16; r += 4) {
        shi[r+0] = __builtin_amdgcn_exp2f(shi[r+0]); a += shi[r+0];
        shi[r+1] = __builtin_amdgcn_exp2f(shi[r+1]); b += shi[r+1];
        shi[r+2] = __builtin_amdgcn_exp2f(shi[r+2]); c += shi[r+2];
        shi[r+3] = __builtin_amdgcn_exp2f(shi[r+3]); d += shi[r+3];
    }
    l += (a + b) + (c + d);
    #pragma unroll
    for (int ks = 0; ks < 4; ++ks) {
        const f32x16& pp = (ks < 2) ? slo : shi;
        const int rb = (ks & 1) * 8;
        u32 X, X2, Y, Y2;
        asm("v_cvt_pk_bf16_f32 %0, %1, %2" : "=v"(X)  : "v"(pp[rb + 0]), "v"(pp[rb + 1]));
        asm("v_cvt_pk_bf16_f32 %0, %1, %2" : "=v"(X2) : "v"(pp[rb + 2]), "v"(pp[rb + 3]));
        asm("v_cvt_pk_bf16_f32 %0, %1, %2" : "=v"(Y)  : "v"(pp[rb + 4]), "v"(pp[rb + 5]));
        asm("v_cvt_pk_bf16_f32 %0, %1, %2" : "=v"(Y2) : "v"(pp[rb + 6]), "v"(pp[rb + 7]));
        asm("v_permlane32_swap_b32 %0, %1" : "+v"(X),  "+v"(Y));
        asm("v_permlane32_swap_b32 %0, %1" : "+v"(X2), "+v"(Y2));
        u32 wds[4] = {X, X2, Y, Y2};
        pa[ks] = *(bf16x8*)wds;
    }
}

// ---------------- main: 128 t/WG, 4 waves x 32 t, no barriers in s-loop ----------------
__global__ __launch_bounds__(256, 4)
void attn_main(const char* __restrict__ ws, float* __restrict__ out)
{
    const int tid  = threadIdx.x;
    const int lane = tid & 63;
    const int w    = tid >> 6;     // wave 0..3, owns t rows [w*32, w*32+32)
    const int hi   = lane >> 5;
    const int ll5  = lane & 31;

    // bid&7 = XCD (round-robin dispatch). Per XCD: j in 0..127; co-resident WGs
    // share a head -> K/V tiles are L1/L2 temporal hits.
    const int bid  = blockIdx.x;
    const int j    = bid >> 3;
    const int head = (bid & 7) * 8 + (j & 7);
    const int tblk = j >> 3;       // 0..15
    const int t0   = tblk * 128;

    const char* Qb = ws + (size_t)head * HSTR + (size_t)t0 * 128;
    const char* Kb = ws + WS_K + (size_t)head * HSTR;
    const char* Vb = ws + WS_V + (size_t)head * HSTR;

    __shared__ __align__(16) char lds[32768];   // Q stage (16K) -> epilogue Of (32K)

    // stage Q tile (16 KB) linearly; content is pre-swizzled
    #pragma unroll
    for (int i = 0; i < 4; ++i)
        gload16(Qb + tid * 16 + i * 4096, lds + tid * 16 + i * 4096);
    asm volatile("s_waitcnt vmcnt(0)");
    __syncthreads();

    // hoist Q fragments: B operand, n = t = w*32+ll5, k = c = kc*16+hi*8+b
    bf16x8 qf[4];
    #pragma unroll
    for (int kc = 0; kc < 4; ++kc)
        qf[kc] = *(const bf16x8*)(lds + swzK(w * 32 + ll5, kc * 32 + hi * 16));

    const int voff = hi * 512 + ll5 * 16;      // per-lane offset within a frag block

    f32x16 o0 = {}, o1 = {};       // O[t][c]: t = w*32+(r&3)+8(r>>2)+4hi, c = ch*32+ll5
    float l_r = 0.f;               // partial row-sum for t = w*32+ll5 (half per hi)

    #pragma unroll 1
    for (int i = 0; i < 32; ++i) {
        const char* Kt = Kb + (size_t)i * 8192 + voff;
        const char* Vt = Vb + (size_t)i * 8192 + voff;

        // ---- QK: S[s][t], A=K frag (m=s, both row-halves), B=Q frag (n=t) ----
        f32x16 sa = {}, sb = {};
        #pragma unroll
        for (int kc = 0; kc < 4; ++kc) {
            bf16x8 k0 = *(const bf16x8*)(Kt + kc * 2048);
            bf16x8 k1 = *(const bf16x8*)(Kt + kc * 2048 + 1024);
            sa = __builtin_amdgcn_mfma_f32_32x32x16_bf16(k0, qf[kc], sa, 0, 0, 0);
            sb = __builtin_amdgcn_mfma_f32_32x32x16_bf16(k1, qf[kc], sb, 0, 0, 0);
        }

        // ---- softmax (fixed-shift, scale pre-folded) + P-frag build ----
        bf16x8 pa[4];
        expcvt(sa, sb, l_r, pa);

        // ---- O += P@V: A=pa (m=t), B=V frag (n=c, both c-halves), at use ----
        #pragma unroll
        for (int ks = 0; ks < 4; ++ks) {
            bf16x8 b0 = *(const bf16x8*)(Vt + ks * 2048);
            bf16x8 b1 = *(const bf16x8*)(Vt + ks * 2048 + 1024);
            o0 = __builtin_amdgcn_mfma_f32_32x32x16_bf16(pa[ks], b0, o0, 0, 0, 0);
            o1 = __builtin_amdgcn_mfma_f32_32x32x16_bf16(pa[ks], b1, o1, 0, 0, 0);
        }
    }

    // ---- epilogue ----
    const float lf = l_r + __shfl_xor(l_r, 32);
    const float linv = 1.0f / lf;   // valid for t = w*32 + ll5
    float li[16];
    #pragma unroll
    for (int r = 0; r < 16; ++r)
        li[r] = __shfl(linv, (r & 3) + 8 * (r >> 2) + 4 * hi);
    #pragma unroll
    for (int r = 0; r < 16; ++r) { o0[r] *= li[r]; o1[r] *= li[r]; }

    __syncthreads();                // all waves done reading Q LDS; reuse as Of
    float* Of = (float*)lds;        // [64 c][128 t] f32, swizzled
    #pragma unroll
    for (int jj = 0; jj < 4; ++jj) {
        const int tb = w * 32 + 8 * jj + 4 * hi;
        f32x4 u0, u1;
        #pragma unroll
        for (int r = 0; r < 4; ++r) { u0[r] = o0[4 * jj + r]; u1[r] = o1[4 * jj + r]; }
        *(f32x4*)((char*)Of + swzO(ll5,      tb * 4)) = u0;
        *(f32x4*)((char*)Of + swzO(32 + ll5, tb * 4)) = u1;
    }
    __syncthreads();

    float* op = out + (size_t)head * DCH * NLEN + t0;
    #pragma unroll
    for (int ch = 0; ch < 8; ++ch) {
        const int idx = tid + ch * 256;     // 0..2047
        const int c = idx >> 5, tq = idx & 31;
        f32x4 v = *(const f32x4*)((char*)Of + swzO(c, tq * 16));
        *(float4*)(op + (size_t)c * NLEN + tq * 4) = *(float4*)&v;
    }
}

// ---------------- fallback (R2 kernel) if ws is too small ----------------
#define QSCALE_FB 0.35355339059327373f
__global__ __launch_bounds__(512, 2)
void attn_fwd(const float* __restrict__ qkv, float* __restrict__ out)
{
    const int tid  = threadIdx.x;
    const int lane = tid & 63;
    const int w    = tid >> 6;
    const int lg   = lane >> 4;
    const int ll   = lane & 15;
    const int tblk = blockIdx.x;
    const int head = blockIdx.y;
    const int t0   = tblk * 128;

    const float* qp = qkv + (size_t)head * (3 * DCH) * NLEN;
    const float* kp = qp + (size_t)DCH * NLEN;
    const float* vp = kp + (size_t)DCH * NLEN;

    __shared__ __align__(16) char lds[48 * 1024];
    char* Qs = lds;
    char* Ks = lds + 16 * 1024;
    char* Vs = lds + 24 * 1024;
    char* Ps = lds + 32 * 1024 + w * 2048;

    {
        const int G = tid >> 6;
        #pragma unroll
        for (int it = 0; it < 2; ++it) {
            const int t = (tid & 63) + it * 64;
            const float* src = qp + (size_t)(G * 8) * NLEN + t0 + t;
            bf16 tmp[8];
            #pragma unroll
            for (int j = 0; j < 8; ++j) tmp[j] = (bf16)(src[(size_t)j * NLEN] * QSCALE_FB);
            *(bf16x8*)(Qs + swzK(t, G * 16)) = *(bf16x8*)tmp;
        }
    }
    __syncthreads();
    bf16x8 qf[2];
    #pragma unroll
    for (int kk = 0; kk < 2; ++kk)
        qf[kk] = *(const bf16x8*)(Qs + swzK(w * 16 + ll, kk * 64 + lg * 16));

    f32x4 o[4] = {};
    float m_r = -3.0e38f, l_r = 0.f;

    for (int sb = 0; sb < NLEN / 64; ++sb) {
        const int s0 = sb * 64;
        __syncthreads();
        {
            const int s = tid & 63, G = tid >> 6;
            const float* src = kp + (size_t)(G * 8) * NLEN + s0 + s;
            bf16 tmp[8];
            #pragma unroll
            for (int j = 0; j < 8; ++j) tmp[j] = (bf16)(src[(size_t)j * NLEN] * QSCALE_FB);
            *(bf16x8*)(Ks + swzK(s, G * 16)) = *(bf16x8*)tmp;
        }
        {
            const int c = tid >> 3, s8 = tid & 7;
            const float* src = vp + (size_t)c * NLEN + s0 + s8 * 8;
            const float4 f0 = *(const float4*)src;
            const float4 f1 = *(const float4*)(src + 4);
            bf16 tmp[8] = {(bf16)f0.x, (bf16)f0.y, (bf16)f0.z, (bf16)f0.w,
                           (bf16)f1.x, (bf16)f1.y, (bf16)f1.z, (bf16)f1.w};
            *(bf16x8*)(Vs + swzK(c, s8 * 16)) = *(bf16x8*)tmp;
        }
        __syncthreads();

        f32x4 sf[4] = {};
        #pragma unroll
        for (int kk = 0; kk < 2; ++kk)
            #pragma unroll
            for (int fs = 0; fs < 4; ++fs) {
                bf16x8 a = *(const bf16x8*)(Ks + swzK(fs * 16 + ll, kk * 64 + lg * 16));
                sf[fs] = __builtin_amdgcn_mfma_f32_16x16x32_bf16(a, qf[kk], sf[fs], 0, 0, 0);
            }

        float mx;
        {
            f32x4 m4 = sf[0];
            #pragma unroll
            for (int fs = 1; fs < 4; ++fs) {
                m4[0] = fmaxf(m4[0], sf[fs][0]); m4[1] = fmaxf(m4[1], sf[fs][1]);
                m4[2] = fmaxf(m4[2], sf[fs][2]); m4[3] = fmaxf(m4[3], sf[fs][3]);
            }
            mx = fmaxf(fmaxf(m4[0], m4[1]), fmaxf(m4[2], m4[3]));
        }
        mx = fmaxf(mx, __shfl_xor(mx, 16));
        mx = fmaxf(mx, __shfl_xor(mx, 32));
        const float mnew = fmaxf(m_r, mx);
        const float corr = exp2f((m_r - mnew) * 1.4426950408889634f);
        m_r = mnew;
        const float cm = mnew * 1.4426950408889634f;

        float psum = 0.f;
        #pragma unroll
        for (int fs = 0; fs < 4; ++fs) {
            bf16x4 pw;
            #pragma unroll
            for (int r = 0; r < 4; ++r) {
                float p = exp2f(fmaf(sf[fs][r], 1.4426950408889634f, -cm));
                psum += p;
                pw[r] = (bf16)p;
            }
            *(bf16x4*)(Ps + swzK(ll, 32 * fs + 8 * lg)) = pw;
        }
        psum += __shfl_xor(psum, 16);
        psum += __shfl_xor(psum, 32);
        l_r = l_r * corr + psum;

        float corr4[4];
        #pragma unroll
        for (int r = 0; r < 4; ++r) corr4[r] = __shfl(corr, 4 * lg + r);
        #pragma unroll
        for (int cf = 0; cf < 4; ++cf)
            #pragma unroll
            for (int r = 0; r < 4; ++r) o[cf][r] *= corr4[r];

        #pragma unroll
        for (int kk = 0; kk < 2; ++kk) {
            bf16x8 pa = *(const bf16x8*)(Ps + swzK(ll, kk * 64 + lg * 16));
            #pragma unroll
            for (int cf = 0; cf < 4; ++cf) {
                bf16x8 b = *(const bf16x8*)(Vs + swzK(cf * 16 + ll, kk * 64 + lg * 16));
                o[cf] = __builtin_amdgcn_mfma_f32_16x16x32_bf16(pa, b, o[cf], 0, 0, 0);
            }
        }
    }

    __syncthreads();
    const float linv = 1.0f / l_r;
    float linv4[4];
    #pragma unroll
    for (int r = 0; r < 4; ++r) linv4[r] = __shfl(linv, 4 * lg + r);
    float* Of = (float*)lds;
    #pragma unroll
    for (int cf = 0; cf < 4; ++cf) {
        f32x4 ov;
        #pragma unroll
        for (int r = 0; r < 4; ++r) ov[r] = o[cf][r] * linv4[r];
        *(f32x4*)((char*)Of + swzO(cf * 16 + ll, (w * 16 + 4 * lg) * 4)) = ov;
    }
    __syncthreads();
    float* op = out + (size_t)head * DCH * NLEN + t0;
    #pragma unroll
    for (int it = 0; it < 4; ++it) {
        const int idx = tid + it * 512;
        const int c = idx >> 5, tq = idx & 31;
        f32x4 v = *(const f32x4*)((char*)Of + swzO(c, tq * 16));
        *(float4*)(op + (size_t)c * NLEN + tq * 4) = *(float4*)&v;
    }
}

extern "C" void kernel_launch(void* const* d_in, const int* in_sizes, int n_in,
                              void* d_out, int out_size, void* d_ws, size_t ws_size,
                              hipStream_t stream)
{
    const float* qkv = (const float*)d_in[0];
    float* out = (float*)d_out;
    if (ws_size >= (size_t)WS_NEED) {
        char* ws = (char*)d_ws;
        prep<<<dim3(32, 64, 3), 256, 0, stream>>>(qkv, ws);
        attn_main<<<dim3(1024), 256, 0, stream>>>(ws, out);
    } else {
        attn_fwd<<<dim3(16, 64), 512, 0, stream>>>(qkv, out);
    }
}

// Round 12
// 99.872 us; speedup vs baseline: 6.7663x; 1.1349x over previous
//
#include <hip/hip_runtime.h>

// QKVAttentionLegacy on MI355X. qkv f32 (8,1536,2048) = 64 heads x [192][2048]:
// q rows 0:64, k 64:128, v 128:192, channel-major [c][pos].
// out[head][c][t] = sum_s softmax_s(qk/8)[t][s] v[c][s].
// R12 = R8 (best, 82us main) + overhead elimination:
//  - PV operand swap: mfma(A=V, B=P) -> D[m=c][n=t]; P's A-layout is a valid
//    B-operand (n=lane&31=t, k=8hi+b=s). Output is born [c][t]: per-lane t=ll5,
//    so normalization is the lane's own 1/lf and stores are coalesced dwords.
//    Epilogue LDS transpose + its barriers: deleted.
//  - Q fragments read directly from ws (prep writes Q plain [t][c]); Q LDS
//    stage + barrier: deleted. attn_main uses ZERO LDS and ZERO barriers.
//  - Main loop unchanged from R8: 64 t/wave, 2-wave WGs (128 thr), grid 1024,
//    same-head CU packing, K(i+1) mid-iter prefetch, V at use, 32x32x16 MFMA,
//    in-register P via cvt_pk+permlane32_swap, native v_exp, fixed-shift
//    softmax with exp-scale folded into prep.

typedef __bf16 bf16;
typedef __bf16 bf16x4 __attribute__((ext_vector_type(4)));
typedef __bf16 bf16x8 __attribute__((ext_vector_type(8)));
typedef float  f32x4  __attribute__((ext_vector_type(4)));
typedef float  f32x16 __attribute__((ext_vector_type(16)));
typedef unsigned int u32;

#define NLEN 2048
#define DCH  64
#define HSTR (NLEN * DCH * 2)          // 256 KB per head per array (bytes)
#define WS_K (16u * 1024u * 1024u)
#define WS_V (32u * 1024u * 1024u)
#define WS_NEED (48u * 1024u * 1024u)
// sqrt(0.125 * log2(e)) -- q,k each scaled by this in prep, so S = (qk/8)*log2e
#define PSCALE 0.42466119f

// 128-byte rows, 16B-granule XOR swizzle (involution): G' = G ^ (row&7)  [fallback only]
__device__ __forceinline__ int swzK(int row, int cb) {
    return row * 128 + ((((cb >> 4) ^ row) & 7) << 4) + (cb & 15);
}
// 512-byte f32 rows for the output transpose buffer [fallback only]
__device__ __forceinline__ int swzO(int row, int cb) {
    int g = cb >> 4;
    g = (g & ~7) | ((g ^ row) & 7);
    return row * 512 + (g << 4) + (cb & 15);
}

// ---------------- prep ----------------
// Q: bf16 scaled, transposed to plain [t][c] rows of 128 B (read direct by main).
// K: bf16 scaled, frag-major per 64-s tile: [kc:4][rh:2][hi:2][ll5:32][8 bf16]
//    holding K[s = rh*32+ll5][c = kc*16+hi*8+b]  (A-operand of QK, coalesced).
// V: bf16 unscaled, frag-major per 64-s tile: [ks:4][rh:2][hi:2][ll5:32][8 bf16]
//    holding V[c = rh*32+ll5][s = ks*16+hi*8+b]  (A-operand of PV, coalesced).
__global__ __launch_bounds__(256)
void prep(const float* __restrict__ qkv, char* __restrict__ ws)
{
    const int tid  = threadIdx.x;
    const int pb   = blockIdx.x;    // 64-pos block (0..31)
    const int head = blockIdx.y;    // 0..63
    const int type = blockIdx.z;    // 0=q 1=k 2=v

    const float* src = qkv + (size_t)head * (3 * DCH) * NLEN + (size_t)type * DCH * NLEN;
    char* dst = ws + (type == 0 ? 0u : (type == 1 ? WS_K : WS_V))
                   + (size_t)head * HSTR + (size_t)pb * 8192;

    if (type < 2) {
        __shared__ float T[64][65];   // [pos][c], +1 pad
        #pragma unroll
        for (int p = 0; p < 4; ++p) {
            int idx = tid + p * 256;
            int c = idx >> 4, q4 = idx & 15;
            float4 f = *(const float4*)(src + (size_t)c * NLEN + pb * 64 + q4 * 4);
            T[q4 * 4 + 0][c] = f.x * PSCALE;
            T[q4 * 4 + 1][c] = f.y * PSCALE;
            T[q4 * 4 + 2][c] = f.z * PSCALE;
            T[q4 * 4 + 3][c] = f.w * PSCALE;
        }
        __syncthreads();
        #pragma unroll
        for (int p = 0; p < 2; ++p) {
            int gidx = tid + p * 256;
            int s = gidx >> 3, G = gidx & 7;
            if (type == 0) {
                // plain [t][c] rows (no swizzle; main reads 16B frags directly)
                bf16 tmp[8];
                #pragma unroll
                for (int j = 0; j < 8; ++j) tmp[j] = (bf16)T[s][G * 8 + j];
                *(bf16x8*)(dst + s * 128 + G * 16) = *(bf16x8*)tmp;
            } else {
                // frag-major K: c-elems G*8..G*8+7 of row s
                const int kc = G >> 1, hi = G & 1;
                bf16 tmp[8];
                #pragma unroll
                for (int j = 0; j < 8; ++j) tmp[j] = (bf16)T[s][G * 8 + j];
                *(bf16x8*)(dst + kc * 2048 + ((s >> 5) & 1) * 1024 + hi * 512
                               + (s & 31) * 16) = *(bf16x8*)tmp;
            }
        }
    } else {
        const int c = tid >> 2, m = tid & 3;      // m = ks
        const float* sp = src + (size_t)c * NLEN + pb * 64 + m * 16;
        float f[16];
        #pragma unroll
        for (int j = 0; j < 4; ++j) *(f32x4*)(f + 4 * j) = *(const f32x4*)(sp + 4 * j);
        #pragma unroll
        for (int gl = 0; gl < 2; ++gl) {          // gl = hi
            bf16 tmp[8];
            #pragma unroll
            for (int j = 0; j < 8; ++j) tmp[j] = (bf16)f[gl * 8 + j];
            *(bf16x8*)(dst + m * 2048 + ((c >> 5) & 1) * 1024 + gl * 512
                           + (c & 31) * 16) = *(bf16x8*)tmp;
        }
    }
}

// exp2 + l-sum + cvt_pk/permlane32_swap: S-half (rows 0-31 = slo, 32-63 = shi,
// one t-half) -> P fragments pa[0..3] (usable as MFMA A- or B-operand)
__device__ __forceinline__ void expcvt(f32x16& slo, f32x16& shi, float& l, bf16x8 pa[4])
{
    float a = 0.f, b = 0.f, c = 0.f, d = 0.f;
    #pragma unroll
    for (int r = 0; r < 16; r += 4) {
        slo[r+0] = __builtin_amdgcn_exp2f(slo[r+0]); a += slo[r+0];
        slo[r+1] = __builtin_amdgcn_exp2f(slo[r+1]); b += slo[r+1];
        slo[r+2] = __builtin_amdgcn_exp2f(slo[r+2]); c += slo[r+2];
        slo[r+3] = __builtin_amdgcn_exp2f(slo[r+3]); d += slo[r+3];
    }
    #pragma unroll
    for (int r = 0; r < 16; r += 4) {
        shi[r+0] = __builtin_amdgcn_exp2f(shi[r+0]); a += shi[r+0];
        shi[r+1] = __builtin_amdgcn_exp2f(shi[r+1]); b += shi[r+1];
        shi[r+2] = __builtin_amdgcn_exp2f(shi[r+2]); c += shi[r+2];
        shi[r+3] = __builtin_amdgcn_exp2f(shi[r+3]); d += shi[r+3];
    }
    l += (a + b) + (c + d);
    #pragma unroll
    for (int ks = 0; ks < 4; ++ks) {
        const f32x16& pp = (ks < 2) ? slo : shi;
        const int rb = (ks & 1) * 8;
        u32 X, X2, Y, Y2;
        asm("v_cvt_pk_bf16_f32 %0, %1, %2" : "=v"(X)  : "v"(pp[rb + 0]), "v"(pp[rb + 1]));
        asm("v_cvt_pk_bf16_f32 %0, %1, %2" : "=v"(X2) : "v"(pp[rb + 2]), "v"(pp[rb + 3]));
        asm("v_cvt_pk_bf16_f32 %0, %1, %2" : "=v"(Y)  : "v"(pp[rb + 4]), "v"(pp[rb + 5]));
        asm("v_cvt_pk_bf16_f32 %0, %1, %2" : "=v"(Y2) : "v"(pp[rb + 6]), "v"(pp[rb + 7]));
        asm("v_permlane32_swap_b32 %0, %1" : "+v"(X),  "+v"(Y));
        asm("v_permlane32_swap_b32 %0, %1" : "+v"(X2), "+v"(Y2));
        u32 wds[4] = {X, X2, Y, Y2};
        pa[ks] = *(bf16x8*)wds;
    }
}

// ---------------- main: 128 t/WG, 2 waves x 64 t, ZERO LDS / ZERO barriers ----------------
__global__ __launch_bounds__(128, 2)
void attn_main(const char* __restrict__ ws, float* __restrict__ out)
{
    const int tid  = threadIdx.x;
    const int lane = tid & 63;
    const int w    = tid >> 6;     // wave 0..1, owns t rows [w*64, w*64+64)
    const int hi   = lane >> 5;
    const int ll5  = lane & 31;

    // bid&7 = XCD (round-robin dispatch). Per XCD: j in 0..127; co-resident WGs
    // share a head and sweep s in the same order -> K/V frags are L1/L2 hits.
    const int bid  = blockIdx.x;
    const int j    = bid >> 3;
    const int head = (bid & 7) * 8 + (j & 7);
    const int tblk = j >> 3;       // 0..15
    const int t0   = tblk * 128;

    const char* Qb = ws + (size_t)head * HSTR + (size_t)t0 * 128;
    const char* Kb = ws + WS_K + (size_t)head * HSTR;
    const char* Vb = ws + WS_V + (size_t)head * HSTR;

    // hoist Q fragments straight from ws ([t][c] rows): B operand of QK,
    // n = t = w*64 + th*32 + ll5, k = c = kc*16 + hi*8 + b. 16B/lane x 8.
    bf16x8 qf0[4], qf1[4];
    #pragma unroll
    for (int kc = 0; kc < 4; ++kc) {
        qf0[kc] = *(const bf16x8*)(Qb + (size_t)(w * 64 + ll5) * 128      + kc * 32 + hi * 16);
        qf1[kc] = *(const bf16x8*)(Qb + (size_t)(w * 64 + 32 + ll5) * 128 + kc * 32 + hi * 16);
    }

    const int voff = hi * 512 + ll5 * 16;      // per-lane offset within a frag block

    // prologue: K fragments of tile 0
    bf16x8 kf0[4], kf1[4];
    #pragma unroll
    for (int kc = 0; kc < 4; ++kc) {
        kf0[kc] = *(const bf16x8*)(Kb + voff + kc * 2048);
        kf1[kc] = *(const bf16x8*)(Kb + voff + kc * 2048 + 1024);
    }

    // O accumulators, TRANSPOSED: o{c-half}{t-half}[r] = O[c][t],
    // c = ch*32 + (r&3)+8*(r>>2)+4*hi, t = w*64 + th*32 + ll5.
    f32x16 o00 = {}, o01 = {}, o10 = {}, o11 = {};
    float l0 = 0.f, l1 = 0.f;

    #pragma unroll 1
    for (int i = 0; i < 32; ++i) {
        const char* Vt = Vb + (size_t)i * 8192 + voff;

        // ---- QK t-half0: S^T[s][t], A=K frag (m=s), B=Q frag (n=t) ----
        f32x16 sa = {}, sb = {};
        #pragma unroll
        for (int kc = 0; kc < 4; ++kc) {
            sa = __builtin_amdgcn_mfma_f32_32x32x16_bf16(kf0[kc], qf0[kc], sa, 0, 0, 0);
            sb = __builtin_amdgcn_mfma_f32_32x32x16_bf16(kf1[kc], qf0[kc], sb, 0, 0, 0);
        }
        bf16x8 pa0[4];
        expcvt(sa, sb, l0, pa0);

        // ---- QK t-half1 ----
        f32x16 sc = {}, sd = {};
        #pragma unroll
        for (int kc = 0; kc < 4; ++kc) {
            sc = __builtin_amdgcn_mfma_f32_32x32x16_bf16(kf0[kc], qf1[kc], sc, 0, 0, 0);
            sd = __builtin_amdgcn_mfma_f32_32x32x16_bf16(kf1[kc], qf1[kc], sd, 0, 0, 0);
        }

        // prefetch K(i+1) fragments (K frags now dead; exp+PV slack covers hit)
        if (i != 31) {
            const char* Kt = Kb + (size_t)(i + 1) * 8192 + voff;
            #pragma unroll
            for (int kc = 0; kc < 4; ++kc) {
                kf0[kc] = *(const bf16x8*)(Kt + kc * 2048);
                kf1[kc] = *(const bf16x8*)(Kt + kc * 2048 + 1024);
            }
        }

        bf16x8 pa1[4];
        expcvt(sc, sd, l1, pa1);

        // ---- O += V@P^T (swapped operands): A=V frag (m=c), B=pa (n=t) ----
        #pragma unroll
        for (int ks = 0; ks < 4; ++ks) {
            bf16x8 a0 = *(const bf16x8*)(Vt + ks * 2048);          // c-half 0
            bf16x8 a1 = *(const bf16x8*)(Vt + ks * 2048 + 1024);   // c-half 1
            o00 = __builtin_amdgcn_mfma_f32_32x32x16_bf16(a0, pa0[ks], o00, 0, 0, 0);
            o01 = __builtin_amdgcn_mfma_f32_32x32x16_bf16(a1, pa0[ks], o01, 0, 0, 0);
            o10 = __builtin_amdgcn_mfma_f32_32x32x16_bf16(a0, pa1[ks], o10, 0, 0, 0);
            o11 = __builtin_amdgcn_mfma_f32_32x32x16_bf16(a1, pa1[ks], o11, 0, 0, 0);
        }
    }

    // ---- epilogue: direct coalesced stores, no LDS ----
    const float li0 = 1.0f / (l0 + __shfl_xor(l0, 32));  // this lane's t (t-half 0)
    const float li1 = 1.0f / (l1 + __shfl_xor(l1, 32));  // this lane's t (t-half 1)

    float* opt = out + (size_t)head * DCH * NLEN + t0 + w * 64 + ll5;
    #pragma unroll
    for (int r = 0; r < 16; ++r) {
        const int c = (r & 3) + 8 * (r >> 2) + 4 * hi;
        opt[(size_t)c * NLEN]             = o00[r] * li0;   // c-half0, t-half0
        opt[(size_t)(32 + c) * NLEN]      = o01[r] * li0;   // c-half1, t-half0
        opt[(size_t)c * NLEN + 32]        = o10[r] * li1;   // c-half0, t-half1
        opt[(size_t)(32 + c) * NLEN + 32] = o11[r] * li1;   // c-half1, t-half1
    }
}

// ---------------- fallback (R2 kernel) if ws is too small ----------------
#define QSCALE_FB 0.35355339059327373f
__global__ __launch_bounds__(512, 2)
void attn_fwd(const float* __restrict__ qkv, float* __restrict__ out)
{
    const int tid  = threadIdx.x;
    const int lane = tid & 63;
    const int w    = tid >> 6;
    const int lg   = lane >> 4;
    const int ll   = lane & 15;
    const int tblk = blockIdx.x;
    const int head = blockIdx.y;
    const int t0   = tblk * 128;

    const float* qp = qkv + (size_t)head * (3 * DCH) * NLEN;
    const float* kp = qp + (size_t)DCH * NLEN;
    const float* vp = kp + (size_t)DCH * NLEN;

    __shared__ __align__(16) char lds[48 * 1024];
    char* Qs = lds;
    char* Ks = lds + 16 * 1024;
    char* Vs = lds + 24 * 1024;
    char* Ps = lds + 32 * 1024 + w * 2048;

    {
        const int G = tid >> 6;
        #pragma unroll
        for (int it = 0; it < 2; ++it) {
            const int t = (tid & 63) + it * 64;
            const float* src = qp + (size_t)(G * 8) * NLEN + t0 + t;
            bf16 tmp[8];
            #pragma unroll
            for (int j = 0; j < 8; ++j) tmp[j] = (bf16)(src[(size_t)j * NLEN] * QSCALE_FB);
            *(bf16x8*)(Qs + swzK(t, G * 16)) = *(bf16x8*)tmp;
        }
    }
    __syncthreads();
    bf16x8 qf[2];
    #pragma unroll
    for (int kk = 0; kk < 2; ++kk)
        qf[kk] = *(const bf16x8*)(Qs + swzK(w * 16 + ll, kk * 64 + lg * 16));

    f32x4 o[4] = {};
    float m_r = -3.0e38f, l_r = 0.f;

    for (int sb = 0; sb < NLEN / 64; ++sb) {
        const int s0 = sb * 64;
        __syncthreads();
        {
            const int s = tid & 63, G = tid >> 6;
            const float* src = kp + (size_t)(G * 8) * NLEN + s0 + s;
            bf16 tmp[8];
            #pragma unroll
            for (int j = 0; j < 8; ++j) tmp[j] = (bf16)(src[(size_t)j * NLEN] * QSCALE_FB);
            *(bf16x8*)(Ks + swzK(s, G * 16)) = *(bf16x8*)tmp;
        }
        {
            const int c = tid >> 3, s8 = tid & 7;
            const float* src = vp + (size_t)c * NLEN + s0 + s8 * 8;
            const float4 f0 = *(const float4*)src;
            const float4 f1 = *(const float4*)(src + 4);
            bf16 tmp[8] = {(bf16)f0.x, (bf16)f0.y, (bf16)f0.z, (bf16)f0.w,
                           (bf16)f1.x, (bf16)f1.y, (bf16)f1.z, (bf16)f1.w};
            *(bf16x8*)(Vs + swzK(c, s8 * 16)) = *(bf16x8*)tmp;
        }
        __syncthreads();

        f32x4 sf[4] = {};
        #pragma unroll
        for (int kk = 0; kk < 2; ++kk)
            #pragma unroll
            for (int fs = 0; fs < 4; ++fs) {
                bf16x8 a = *(const bf16x8*)(Ks + swzK(fs * 16 + ll, kk * 64 + lg * 16));
                sf[fs] = __builtin_amdgcn_mfma_f32_16x16x32_bf16(a, qf[kk], sf[fs], 0, 0, 0);
            }

        float mx;
        {
            f32x4 m4 = sf[0];
            #pragma unroll
            for (int fs = 1; fs < 4; ++fs) {
                m4[0] = fmaxf(m4[0], sf[fs][0]); m4[1] = fmaxf(m4[1], sf[fs][1]);
                m4[2] = fmaxf(m4[2], sf[fs][2]); m4[3] = fmaxf(m4[3], sf[fs][3]);
            }
            mx = fmaxf(fmaxf(m4[0], m4[1]), fmaxf(m4[2], m4[3]));
        }
        mx = fmaxf(mx, __shfl_xor(mx, 16));
        mx = fmaxf(mx, __shfl_xor(mx, 32));
        const float mnew = fmaxf(m_r, mx);
        const float corr = exp2f((m_r - mnew) * 1.4426950408889634f);
        m_r = mnew;
        const float cm = mnew * 1.4426950408889634f;

        float psum = 0.f;
        #pragma unroll
        for (int fs = 0; fs < 4; ++fs) {
            bf16x4 pw;
            #pragma unroll
            for (int r = 0; r < 4; ++r) {
                float p = exp2f(fmaf(sf[fs][r], 1.4426950408889634f, -cm));
                psum += p;
                pw[r] = (bf16)p;
            }
            *(bf16x4*)(Ps + swzK(ll, 32 * fs + 8 * lg)) = pw;
        }
        psum += __shfl_xor(psum, 16);
        psum += __shfl_xor(psum, 32);
        l_r = l_r * corr + psum;

        float corr4[4];
        #pragma unroll
        for (int r = 0; r < 4; ++r) corr4[r] = __shfl(corr, 4 * lg + r);
        #pragma unroll
        for (int cf = 0; cf < 4; ++cf)
            #pragma unroll
            for (int r = 0; r < 4; ++r) o[cf][r] *= corr4[r];

        #pragma unroll
        for (int kk = 0; kk < 2; ++kk) {
            bf16x8 pa = *(const bf16x8*)(Ps + swzK(ll, kk * 64 + lg * 16));
            #pragma unroll
            for (int cf = 0; cf < 4; ++cf) {
                bf16x8 b = *(const bf16x8*)(Vs + swzK(cf * 16 + ll, kk * 64 + lg * 16));
                o[cf] = __builtin_amdgcn_mfma_f32_16x16x32_bf16(pa, b, o[cf], 0, 0, 0);
            }
        }
    }

    __syncthreads();
    const float linv = 1.0f / l_r;
    float linv4[4];
    #pragma unroll
    for (int r = 0; r < 4; ++r) linv4[r] = __shfl(linv, 4 * lg + r);
    float* Of = (float*)lds;
    #pragma unroll
    for (int cf = 0; cf < 4; ++cf) {
        f32x4 ov;
        #pragma unroll
        for (int r = 0; r < 4; ++r) ov[r] = o[cf][r] * linv4[r];
        *(f32x4*)((char*)Of + swzO(cf * 16 + ll, (w * 16 + 4 * lg) * 4)) = ov;
    }
    __syncthreads();
    float* op = out + (size_t)head * DCH * NLEN + t0;
    #pragma unroll
    for (int it = 0; it < 4; ++it) {
        const int idx = tid + it * 512;
        const int c = idx >> 5, tq = idx & 31;
        f32x4 v = *(const f32x4*)((char*)Of + swzO(c, tq * 16));
        *(float4*)(op + (size_t)c * NLEN + tq * 4) = *(float4*)&v;
    }
}

extern "C" void kernel_launch(void* const* d_in, const int* in_sizes, int n_in,
                              void* d_out, int out_size, void* d_ws, size_t ws_size,
                              hipStream_t stream)
{
    const float* qkv = (const float*)d_in[0];
    float* out = (float*)d_out;
    if (ws_size >= (size_t)WS_NEED) {
        char* ws = (char*)d_ws;
        prep<<<dim3(32, 64, 3), 256, 0, stream>>>(qkv, ws);
        attn_main<<<dim3(1024), 128, 0, stream>>>(ws, out);
    } else {
        attn_fwd<<<dim3(16, 64), 512, 0, stream>>>(qkv, out);
    }
}